// Round 6
// baseline (184.215 us; speedup 1.0000x reference)
//
#include <hip/hip_runtime.h>
#include <hip/hip_cooperative_groups.h>
#include <math.h>

namespace cgn = cooperative_groups;

#define NN 512
#define DD 512
#define HH 64
#define OUTC 32

// ws layout (floats):
//   P1T  [H][N]   @ 0       (32768)
//   P2B  [N][H]   @ 32768   (legacy path only)
//   XWT  [OUT][N] @ 65536   (16384)
//   RDV  [N]      @ 81920   (512)

// ============================ FUSED COOPERATIVE =============================
// 256 blocks x 512 threads. Block b owns rows i0=2b, i0+1 in every phase.
// A: split-K projections -> p1t, xwt (global); P2+b1 rows stay in LDS (sp2).
// B: adj row pair; raw sigmoid values stay in REGISTERS (a0,a1); rdv -> global.
// C: normalize regs, write outA, A@XW via per-o shuffle reduce, BN+ReLU -> outx.
__global__ __launch_bounds__(512) void fused_all(
    const float* __restrict__ features,
    const float* __restrict__ rel_w1,
    const float* __restrict__ rel_b1,
    const float* __restrict__ rel_w2,
    const float* __restrict__ rel_b2,
    const float* __restrict__ gcn_w,
    const float* __restrict__ gcn_b,
    const float* __restrict__ bn_gamma,
    const float* __restrict__ bn_beta,
    float* __restrict__ p1t,
    float* __restrict__ xwt,
    float* __restrict__ rdv,
    float* __restrict__ outx,
    float* __restrict__ outA)
{
    __shared__ float sredA[2][8][32];
    __shared__ float sp2[2][HH];
    __shared__ float sw2[HH];
    __shared__ float sredB[2][8];
    __shared__ float sdv[NN];
    __shared__ float sredC[2][8][32];

    const int b   = blockIdx.x;
    const int t   = threadIdx.x;
    const int sub = t >> 8;          // 0/1: which of the block's two rows
    const int tl  = t & 255;
    const int i0  = b * 2;
    const int i   = i0 + sub;

    // ---------------- Phase A: C[512][160] = F @ [W1a|W1b|gcn_w], split-K 8
    const int tc = tl & 31;          // col within 32-col group
    const int kc = tl >> 5;          // k-chunk 0..7 (64 k each)
    {
        const float* fp = features + (size_t)i * DD + kc * 64;
        float4 fr[16];
        #pragma unroll
        for (int q = 0; q < 16; ++q) fr[q] = *(const float4*)(fp + 4 * q);

        #pragma unroll
        for (int cgi = 0; cgi < 5; ++cgi) {
            float acc = 0.f;
            if (cgi < 4) {
                const float* wp = rel_w1 + (size_t)(cgi >> 1) * (DD * HH)
                                + (cgi & 1) * 32 + tc + (size_t)kc * 64 * HH;
                #pragma unroll
                for (int q = 0; q < 16; ++q) {
                    acc = fmaf(fr[q].x, wp[(4 * q + 0) * HH], acc);
                    acc = fmaf(fr[q].y, wp[(4 * q + 1) * HH], acc);
                    acc = fmaf(fr[q].z, wp[(4 * q + 2) * HH], acc);
                    acc = fmaf(fr[q].w, wp[(4 * q + 3) * HH], acc);
                }
            } else {
                const float* wp = gcn_w + tc + (size_t)kc * 64 * OUTC;
                #pragma unroll
                for (int q = 0; q < 16; ++q) {
                    acc = fmaf(fr[q].x, wp[(4 * q + 0) * OUTC], acc);
                    acc = fmaf(fr[q].y, wp[(4 * q + 1) * OUTC], acc);
                    acc = fmaf(fr[q].z, wp[(4 * q + 2) * OUTC], acc);
                    acc = fmaf(fr[q].w, wp[(4 * q + 3) * OUTC], acc);
                }
            }
            sredA[sub][kc][tc] = acc;
            __syncthreads();
            if (tl < 32) {
                float s = 0.f;
                #pragma unroll
                for (int k = 0; k < 8; ++k) s += sredA[sub][k][tl];
                if (cgi == 0)      p1t[(size_t)tl * NN + i] = s;
                else if (cgi == 1) p1t[(size_t)(tl + 32) * NN + i] = s;
                else if (cgi < 4) {
                    int h = (cgi - 2) * 32 + tl;
                    sp2[sub][h] = s + rel_b1[h];      // block-local, stays in LDS
                } else {
                    xwt[(size_t)tl * NN + i] = s;
                }
            }
            __syncthreads();
        }
    }
    if (t < HH) sw2[t] = rel_w2[t];

    __threadfence();
    cgn::this_grid().sync();

    // ---------------- Phase B: adjacency row pair, values stay in registers
    const int j = t;                                   // 0..511
    float a0 = rel_b2[0], a1 = a0;
    {
        const float* pj = p1t + j;
        #pragma unroll
        for (int k = 0; k < HH; ++k) {
            float pv = pj[(size_t)k * NN];             // coalesced across lanes
            float w  = sw2[k];
            a0 = fmaf(fmaxf(pv + sp2[0][k], 0.f), w, a0);
            a1 = fmaf(fmaxf(pv + sp2[1][k], 0.f), w, a1);
        }
    }
    a0 = 1.f / (1.f + expf(-a0));
    a1 = 1.f / (1.f + expf(-a1));
    if (j == i0)     a0 += 1.f;
    if (j == i0 + 1) a1 += 1.f;

    {
        float rs0 = a0, rs1 = a1;
        #pragma unroll
        for (int off = 32; off > 0; off >>= 1) {
            rs0 += __shfl_down(rs0, off, 64);
            rs1 += __shfl_down(rs1, off, 64);
        }
        int wv = t >> 6, ln = t & 63;
        if (ln == 0) { sredB[0][wv] = rs0; sredB[1][wv] = rs1; }
        __syncthreads();
        if (t < 2) {
            float s = 0.f;
            #pragma unroll
            for (int w = 0; w < 8; ++w) s += sredB[t][w];
            rdv[i0 + t] = 1.0f / sqrtf(s + 1.0f);
        }
    }

    __threadfence();
    cgn::this_grid().sync();

    // ---------------- Phase C: normalize + A@XW + BN + ReLU
    sdv[t] = rdv[t];                                   // 512 threads cover NN
    __syncthreads();

    const float dj  = sdv[j];
    const float a0n = a0 * (sdv[i0] * dj);
    const float a1n = a1 * (sdv[i0 + 1] * dj);
    outA[(size_t)i0 * NN + j]       = a0n;
    outA[(size_t)(i0 + 1) * NN + j] = a1n;

    const int wv = t >> 6, ln = t & 63;
    #pragma unroll
    for (int o = 0; o < OUTC; ++o) {
        float x  = xwt[(size_t)o * NN + j];            // coalesced, shared by rows
        float p0 = a0n * x;
        float p1 = a1n * x;
        #pragma unroll
        for (int off = 32; off > 0; off >>= 1) {
            p0 += __shfl_down(p0, off, 64);
            p1 += __shfl_down(p1, off, 64);
        }
        if (ln == 0) { sredC[0][wv][o] = p0; sredC[1][wv][o] = p1; }
    }
    __syncthreads();
    if (t < 64) {
        int rr = t >> 5, o = t & 31;
        float v = 0.f;
        #pragma unroll
        for (int w = 0; w < 8; ++w) v += sredC[rr][w][o];
        v += gcn_b[o];
        const float invs = 1.0f / sqrtf(1.0f + 1e-5f);
        v = bn_gamma[o] * v * invs + bn_beta[o];
        outx[(size_t)(i0 + rr) * OUTC + o] = fmaxf(v, 0.f);
    }
}

// ============================ LEGACY FALLBACK ===============================
template<int STRIDE>
__device__ __forceinline__ float dot64(const float* __restrict__ fp,
                                       const float* __restrict__ wp)
{
    float acc = 0.f;
    #pragma unroll
    for (int q = 0; q < 16; ++q) {
        float4 f = *(const float4*)(fp + 4 * q);
        acc = fmaf(f.x, wp[(size_t)(4 * q + 0) * STRIDE], acc);
        acc = fmaf(f.y, wp[(size_t)(4 * q + 1) * STRIDE], acc);
        acc = fmaf(f.z, wp[(size_t)(4 * q + 2) * STRIDE], acc);
        acc = fmaf(f.w, wp[(size_t)(4 * q + 3) * STRIDE], acc);
    }
    return acc;
}

__global__ __launch_bounds__(256) void k1_gemm(
    const float* __restrict__ features, const float* __restrict__ rel_w1,
    const float* __restrict__ rel_b1, const float* __restrict__ gcn_w,
    float* __restrict__ p1t, float* __restrict__ p2b, float* __restrict__ xwt)
{
    __shared__ float sred[8][32];
    const int t  = threadIdx.x;
    const int tc = t & 31;
    const int kc = t >> 5;
    const int cg = blockIdx.x;
    const int i  = blockIdx.y;

    const float* fp = features + (size_t)i * DD + kc * 64;
    float acc;
    if (cg < 2)      acc = dot64<HH>(fp, rel_w1 + cg * 32 + tc + (size_t)kc * 64 * HH);
    else if (cg < 4) acc = dot64<HH>(fp, rel_w1 + (size_t)DD * HH + (cg - 2) * 32 + tc
                                         + (size_t)kc * 64 * HH);
    else             acc = dot64<OUTC>(fp, gcn_w + tc + (size_t)kc * 64 * OUTC);

    sred[kc][tc] = acc;
    __syncthreads();
    if (t < 32) {
        float s = sred[0][t] + sred[1][t] + sred[2][t] + sred[3][t]
                + sred[4][t] + sred[5][t] + sred[6][t] + sred[7][t];
        if (cg < 2)      p1t[(size_t)(cg * 32 + t) * NN + i] = s;
        else if (cg < 4) { int h = (cg - 2) * 32 + t; p2b[(size_t)i * HH + h] = s + rel_b1[h]; }
        else             xwt[(size_t)t * NN + i] = s;
    }
}

__global__ __launch_bounds__(256) void k2_adj(
    const float* __restrict__ p1t, const float* __restrict__ p2b,
    const float* __restrict__ rel_w2, const float* __restrict__ rel_b2,
    float* __restrict__ araw, float* __restrict__ rdv)
{
    const int TI = 2;
    __shared__ float sp2[TI][HH];
    __shared__ float sw2[HH];
    __shared__ float sred[TI][4];
    const int t  = threadIdx.x;
    const int i0 = blockIdx.x * TI;

    if (t < HH) sw2[t] = rel_w2[t];
    else if (t < HH + TI * HH) {
        int q = t - HH;
        sp2[q >> 6][q & 63] = p2b[(size_t)i0 * HH + q];
    }
    __syncthreads();

    const float b2 = rel_b2[0];
    float rs0 = 0.f, rs1 = 0.f;
    #pragma unroll
    for (int jj = 0; jj < 2; ++jj) {
        int j = t + jj * 256;
        float a0 = b2, a1 = b2;
        #pragma unroll 8
        for (int k = 0; k < HH; ++k) {
            float pv = p1t[(size_t)k * NN + j];
            float w  = sw2[k];
            a0 = fmaf(fmaxf(pv + sp2[0][k], 0.f), w, a0);
            a1 = fmaf(fmaxf(pv + sp2[1][k], 0.f), w, a1);
        }
        a0 = 1.f / (1.f + expf(-a0)); if (j == i0)     a0 += 1.f;
        a1 = 1.f / (1.f + expf(-a1)); if (j == i0 + 1) a1 += 1.f;
        araw[(size_t)(i0 + 0) * NN + j] = a0;
        araw[(size_t)(i0 + 1) * NN + j] = a1;
        rs0 += a0; rs1 += a1;
    }
    #pragma unroll
    for (int off = 32; off > 0; off >>= 1) {
        rs0 += __shfl_down(rs0, off, 64);
        rs1 += __shfl_down(rs1, off, 64);
    }
    int wave = t >> 6, lane = t & 63;
    if (lane == 0) { sred[0][wave] = rs0; sred[1][wave] = rs1; }
    __syncthreads();
    if (t < TI) {
        float s = sred[t][0] + sred[t][1] + sred[t][2] + sred[t][3];
        rdv[i0 + t] = 1.0f / sqrtf(s + 1.0f);
    }
}

__global__ __launch_bounds__(256) void k3_gcn(
    const float* __restrict__ xwt, const float* __restrict__ rdv,
    const float* __restrict__ gcn_b, const float* __restrict__ bn_gamma,
    const float* __restrict__ bn_beta, float* __restrict__ outx,
    float* __restrict__ outA)
{
    __shared__ float sdv[NN];
    __shared__ float sred[4][OUTC];
    const int t = threadIdx.x;
    const int i = blockIdx.x;

    sdv[t] = rdv[t];
    sdv[t + 256] = rdv[t + 256];
    __syncthreads();

    const float ri = sdv[i];
    const int j0 = t, j1 = t + 256;
    float a0 = outA[(size_t)i * NN + j0] * (ri * sdv[j0]);
    float a1 = outA[(size_t)i * NN + j1] * (ri * sdv[j1]);
    outA[(size_t)i * NN + j0] = a0;
    outA[(size_t)i * NN + j1] = a1;

    float acc[OUTC];
    #pragma unroll
    for (int o = 0; o < OUTC; ++o)
        acc[o] = fmaf(a0, xwt[(size_t)o * NN + j0], a1 * xwt[(size_t)o * NN + j1]);

    #pragma unroll
    for (int o = 0; o < OUTC; ++o)
        #pragma unroll
        for (int off = 32; off > 0; off >>= 1)
            acc[o] += __shfl_down(acc[o], off, 64);

    int wave = t >> 6, lane = t & 63;
    if (lane == 0) {
        #pragma unroll
        for (int o = 0; o < OUTC; ++o) sred[wave][o] = acc[o];
    }
    __syncthreads();
    if (t < OUTC) {
        float v = sred[0][t] + sred[1][t] + sred[2][t] + sred[3][t] + gcn_b[t];
        const float invs = 1.0f / sqrtf(1.0f + 1e-5f);
        v = bn_gamma[t] * v * invs + bn_beta[t];
        outx[(size_t)i * OUTC + t] = fmaxf(v, 0.f);
    }
}

extern "C" void kernel_launch(void* const* d_in, const int* in_sizes, int n_in,
                              void* d_out, int out_size, void* d_ws, size_t ws_size,
                              hipStream_t stream) {
    const float* features = (const float*)d_in[0];
    const float* rel_w1   = (const float*)d_in[1];
    const float* rel_b1   = (const float*)d_in[2];
    const float* rel_w2   = (const float*)d_in[3];
    const float* rel_b2   = (const float*)d_in[4];
    const float* gcn_w    = (const float*)d_in[5];
    const float* gcn_b    = (const float*)d_in[6];
    const float* bn_gamma = (const float*)d_in[7];
    const float* bn_beta  = (const float*)d_in[8];

    float* out  = (float*)d_out;
    float* outx = out;                 // (512, 32)
    float* outA = out + NN * OUTC;     // (512, 512)

    float* ws  = (float*)d_ws;
    float* p1t = ws;                   // [64][512]
    float* p2b = ws + 32768;           // [512][64] (legacy only)
    float* xwt = ws + 65536;           // [32][512]
    float* rdv = ws + 81920;           // [512]

    void* args[] = {
        (void*)&features, (void*)&rel_w1, (void*)&rel_b1, (void*)&rel_w2,
        (void*)&rel_b2, (void*)&gcn_w, (void*)&gcn_b, (void*)&bn_gamma,
        (void*)&bn_beta, (void*)&p1t, (void*)&xwt, (void*)&rdv,
        (void*)&outx, (void*)&outA
    };
    hipError_t e = hipLaunchCooperativeKernel((const void*)fused_all,
                                              dim3(256), dim3(512),
                                              args, 0, stream);
    if (e != hipSuccess) {
        // fallback: proven 3-kernel path
        hipLaunchKernelGGL(k1_gemm, dim3(5, 512), dim3(256), 0, stream,
                           features, rel_w1, rel_b1, gcn_w, p1t, p2b, xwt);
        hipLaunchKernelGGL(k2_adj, dim3(256), dim3(256), 0, stream,
                           p1t, p2b, rel_w2, rel_b2, outA, rdv);
        hipLaunchKernelGGL(k3_gcn, dim3(512), dim3(256), 0, stream,
                           xwt, rdv, gcn_b, bn_gamma, bn_beta, outx, outA);
    }
}

// Round 7
// 36.193 us; speedup vs baseline: 5.0898x; 5.0898x over previous
//
#include <hip/hip_runtime.h>
#include <math.h>

#define NN 512
#define DD 512
#define HH 64
#define OUTC 32

// ws layout (floats) — ALL row-major now:
//   P1   [N][H]   @ 0      (32768)   P1[j][h]  = (F @ W1[:D])[j][h]
//   P2B  [N][H]   @ 32768  (32768)   P2B[i][h] = (F @ W1[D:])[i][h] + b1[h]
//   XW   [N][OUT] @ 65536  (16384)   XW[j][o]  = (F @ gcn_w)[j][o]
//   RDV  [N]      @ 81920  (512)     rdv[i] = 1/sqrt(rowsum(A)+1)

// 64-term partial dot, compile-time W stride (split-K; occupancy is the
// latency-hiding mechanism — 40 waves/CU requested).
template<int STRIDE>
__device__ __forceinline__ float dot64(const float* __restrict__ fp,
                                       const float* __restrict__ wp)
{
    float acc = 0.f;
    #pragma unroll
    for (int q = 0; q < 16; ++q) {
        float4 f = *(const float4*)(fp + 4 * q);
        acc = fmaf(f.x, wp[(size_t)(4 * q + 0) * STRIDE], acc);
        acc = fmaf(f.y, wp[(size_t)(4 * q + 1) * STRIDE], acc);
        acc = fmaf(f.z, wp[(size_t)(4 * q + 2) * STRIDE], acc);
        acc = fmaf(f.w, wp[(size_t)(4 * q + 3) * STRIDE], acc);
    }
    return acc;
}

// K1: C[512][160] = F @ [W1a | W1b | gcn_w], split-K 8.
// grid (cg=0..4, i=0..511); thread: tc = t&31, kc = t>>5.
__global__ __launch_bounds__(256) void k1_gemm(
    const float* __restrict__ features,
    const float* __restrict__ rel_w1,
    const float* __restrict__ rel_b1,
    const float* __restrict__ gcn_w,
    float* __restrict__ p1,
    float* __restrict__ p2b,
    float* __restrict__ xw)
{
    __shared__ float sred[8][32];
    const int t  = threadIdx.x;
    const int tc = t & 31;
    const int kc = t >> 5;
    const int cg = blockIdx.x;          // 0..4
    const int i  = blockIdx.y;          // 0..511

    const float* fp = features + (size_t)i * DD + kc * 64;

    float acc;
    if (cg < 2)
        acc = dot64<HH>(fp, rel_w1 + cg * 32 + tc + (size_t)kc * 64 * HH);
    else if (cg < 4)
        acc = dot64<HH>(fp, rel_w1 + (size_t)DD * HH + (cg - 2) * 32 + tc
                            + (size_t)kc * 64 * HH);
    else
        acc = dot64<OUTC>(fp, gcn_w + tc + (size_t)kc * 64 * OUTC);

    sred[kc][tc] = acc;
    __syncthreads();

    if (t < 32) {
        float s = sred[0][t] + sred[1][t] + sred[2][t] + sred[3][t]
                + sred[4][t] + sred[5][t] + sred[6][t] + sred[7][t];
        if (cg < 2) {
            p1[(size_t)i * HH + cg * 32 + t] = s;          // row-major
        } else if (cg < 4) {
            int h = (cg - 2) * 32 + t;
            p2b[(size_t)i * HH + h] = s + rel_b1[h];       // row-major
        } else {
            xw[(size_t)i * OUTC + t] = s;                  // row-major
        }
    }
}

// K2: one block per row i, one thread per j.
// araw[i][j] = sigmoid(relu(P1[j]+P2b[i]) . w2 + b2) + (i==j); rdv[i].
__global__ __launch_bounds__(512) void k2_adj(
    const float* __restrict__ p1,
    const float* __restrict__ p2b,
    const float* __restrict__ rel_w2,
    const float* __restrict__ rel_b2,
    float* __restrict__ araw,     // d_out A region (raw; normalized in k3)
    float* __restrict__ rdv)
{
    __shared__ float sp2[HH];
    __shared__ float sw2[HH];
    __shared__ float sred[8];
    const int t = threadIdx.x;    // j
    const int i = blockIdx.x;

    if (t < HH)             sp2[t] = p2b[(size_t)i * HH + t];
    else if (t < 2 * HH)    sw2[t - HH] = rel_w2[t - HH];
    __syncthreads();

    // p1 row j: 16 contiguous float4 loads (vectorized, independent)
    const float4* pr = (const float4*)(p1 + (size_t)t * HH);
    float a = rel_b2[0];
    #pragma unroll
    for (int q = 0; q < 16; ++q) {
        float4 v = pr[q];
        a = fmaf(fmaxf(v.x + sp2[4 * q + 0], 0.f), sw2[4 * q + 0], a);
        a = fmaf(fmaxf(v.y + sp2[4 * q + 1], 0.f), sw2[4 * q + 1], a);
        a = fmaf(fmaxf(v.z + sp2[4 * q + 2], 0.f), sw2[4 * q + 2], a);
        a = fmaf(fmaxf(v.w + sp2[4 * q + 3], 0.f), sw2[4 * q + 3], a);
    }
    a = 1.f / (1.f + expf(-a));
    if (t == i) a += 1.f;
    araw[(size_t)i * NN + t] = a;

    float rs = a;
    #pragma unroll
    for (int off = 32; off > 0; off >>= 1) rs += __shfl_down(rs, off, 64);
    const int wv = t >> 6, ln = t & 63;
    if (ln == 0) sred[wv] = rs;
    __syncthreads();
    if (t == 0) {
        float s = 0.f;
        #pragma unroll
        for (int w = 0; w < 8; ++w) s += sred[w];
        rdv[i] = 1.0f / sqrtf(s + 1.0f);
    }
}

// K3: one block per row i, one thread per j. Normalize A in place,
// x[i] = relu(gamma * (A[i,:] @ XW + b) * inv_sqrt(1+eps) + beta).
__global__ __launch_bounds__(512) void k3_gcn(
    const float* __restrict__ xw,
    const float* __restrict__ rdv,
    const float* __restrict__ gcn_b,
    const float* __restrict__ bn_gamma,
    const float* __restrict__ bn_beta,
    float* __restrict__ outx,
    float* __restrict__ outA)
{
    __shared__ float sdv[NN];
    __shared__ float sred[8][OUTC];
    const int t = threadIdx.x;    // j
    const int i = blockIdx.x;

    sdv[t] = rdv[t];
    __syncthreads();

    const float an = outA[(size_t)i * NN + t] * (sdv[i] * sdv[t]);
    outA[(size_t)i * NN + t] = an;

    // xw row j: 8 contiguous float4 loads
    const float4* xr = (const float4*)(xw + (size_t)t * OUTC);
    float acc[OUTC];
    #pragma unroll
    for (int q = 0; q < 8; ++q) {
        float4 v = xr[q];
        acc[4 * q + 0] = an * v.x;
        acc[4 * q + 1] = an * v.y;
        acc[4 * q + 2] = an * v.z;
        acc[4 * q + 3] = an * v.w;
    }

    #pragma unroll
    for (int o = 0; o < OUTC; ++o)
        #pragma unroll
        for (int off = 32; off > 0; off >>= 1)
            acc[o] += __shfl_down(acc[o], off, 64);

    const int wv = t >> 6, ln = t & 63;
    if (ln == 0) {
        #pragma unroll
        for (int o = 0; o < OUTC; ++o) sred[wv][o] = acc[o];
    }
    __syncthreads();
    if (t < OUTC) {
        float v = gcn_b[t];
        #pragma unroll
        for (int w = 0; w < 8; ++w) v += sred[w][t];
        const float invs = 1.0f / sqrtf(1.0f + 1e-5f);
        v = bn_gamma[t] * v * invs + bn_beta[t];
        outx[(size_t)i * OUTC + t] = fmaxf(v, 0.f);
    }
}

extern "C" void kernel_launch(void* const* d_in, const int* in_sizes, int n_in,
                              void* d_out, int out_size, void* d_ws, size_t ws_size,
                              hipStream_t stream) {
    const float* features = (const float*)d_in[0];
    const float* rel_w1   = (const float*)d_in[1];
    const float* rel_b1   = (const float*)d_in[2];
    const float* rel_w2   = (const float*)d_in[3];
    const float* rel_b2   = (const float*)d_in[4];
    const float* gcn_w    = (const float*)d_in[5];
    const float* gcn_b    = (const float*)d_in[6];
    const float* bn_gamma = (const float*)d_in[7];
    const float* bn_beta  = (const float*)d_in[8];

    float* out  = (float*)d_out;
    float* outx = out;                 // (512, 32)
    float* outA = out + NN * OUTC;     // (512, 512)

    float* ws  = (float*)d_ws;
    float* p1  = ws;                   // [512][64]
    float* p2b = ws + 32768;           // [512][64]
    float* xw  = ws + 65536;           // [512][32]
    float* rdv = ws + 81920;           // [512]

    hipLaunchKernelGGL(k1_gemm, dim3(5, 512), dim3(256), 0, stream,
                       features, rel_w1, rel_b1, gcn_w, p1, p2b, xw);
    hipLaunchKernelGGL(k2_adj, dim3(512), dim3(512), 0, stream,
                       p1, p2b, rel_w2, rel_b2, outA, rdv);
    hipLaunchKernelGGL(k3_gcn, dim3(512), dim3(512), 0, stream,
                       xw, rdv, gcn_b, bn_gamma, bn_beta, outx, outA);
}

// Round 8
// 28.726 us; speedup vs baseline: 6.4128x; 1.2599x over previous
//
#include <hip/hip_runtime.h>
#include <math.h>

#define NN 512
#define DD 512
#define HH 64
#define OUTC 32

// ws layout (floats):
//   P1T  [H][N]   @ 0      (32768)   col-major: P1T[h][j] (k2 reads coalesced)
//   P2B  [N][H]   @ 32768  (32768)   row-major
//   XW   [N][OUT] @ 65536  (16384)   row-major: XW[j][o] (k3 reads coalesced)
//   RDV  [N]      @ 81920  (512)

// 16 k-terms x 4 adjacent cols via float4 W loads (compile-time stride).
template<int STRIDE>
__device__ __forceinline__ float4 dot16x4(const float* __restrict__ fp,
                                          const float* __restrict__ wp)
{
    float4 fr[4];
    #pragma unroll
    for (int q = 0; q < 4; ++q) fr[q] = *(const float4*)(fp + 4 * q);
    const float fs[16] = {fr[0].x, fr[0].y, fr[0].z, fr[0].w,
                          fr[1].x, fr[1].y, fr[1].z, fr[1].w,
                          fr[2].x, fr[2].y, fr[2].z, fr[2].w,
                          fr[3].x, fr[3].y, fr[3].z, fr[3].w};
    float4 acc = make_float4(0.f, 0.f, 0.f, 0.f);
    #pragma unroll
    for (int q = 0; q < 16; ++q) {
        float4 w = *(const float4*)(wp + (size_t)q * STRIDE);
        acc.x = fmaf(fs[q], w.x, acc.x);
        acc.y = fmaf(fs[q], w.y, acc.y);
        acc.z = fmaf(fs[q], w.z, acc.z);
        acc.w = fmaf(fs[q], w.w, acc.w);
    }
    return acc;
}

// K1: C[512][160] = F @ [W1a | W1b | gcn_w], split-K 32, 4 cols/thread.
// grid (cg=0..4, i=0..511) x 256 thr; tq = t&7 (col quad), kc = t>>3 (16 k).
__global__ __launch_bounds__(256) void k1_gemm(
    const float* __restrict__ features,
    const float* __restrict__ rel_w1,
    const float* __restrict__ rel_b1,
    const float* __restrict__ gcn_w,
    float* __restrict__ p1t,
    float* __restrict__ p2b,
    float* __restrict__ xw)
{
    __shared__ float sred[32][33];       // +1 pad: conflict-free column sums
    const int t  = threadIdx.x;
    const int tq = t & 7;
    const int kc = t >> 3;
    const int cg = blockIdx.x;
    const int i  = blockIdx.y;

    const float* fp = features + (size_t)i * DD + kc * 16;

    float4 a4;
    if (cg < 2)
        a4 = dot16x4<HH>(fp, rel_w1 + cg * 32 + tq * 4 + (size_t)kc * 16 * HH);
    else if (cg < 4)
        a4 = dot16x4<HH>(fp, rel_w1 + (size_t)DD * HH + (cg - 2) * 32 + tq * 4
                             + (size_t)kc * 16 * HH);
    else
        a4 = dot16x4<OUTC>(fp, gcn_w + tq * 4 + (size_t)kc * 16 * OUTC);

    sred[kc][tq * 4 + 0] = a4.x;
    sred[kc][tq * 4 + 1] = a4.y;
    sred[kc][tq * 4 + 2] = a4.z;
    sred[kc][tq * 4 + 3] = a4.w;
    __syncthreads();

    if (t < 32) {
        float s = 0.f;
        #pragma unroll
        for (int k = 0; k < 32; ++k) s += sred[k][t];
        if (cg < 2) {
            p1t[(size_t)(cg * 32 + t) * NN + i] = s;       // col-major
        } else if (cg < 4) {
            int h = (cg - 2) * 32 + t;
            p2b[(size_t)i * HH + h] = s + rel_b1[h];
        } else {
            xw[(size_t)i * OUTC + t] = s;                  // row-major
        }
    }
}

// K2: block = row i (512 blocks x 512 thr), thread = col j.
// araw[i][j] = sigmoid(relu(P1[j]+P2b[i]).w2 + b2) + (i==j); rdv[i].
__global__ __launch_bounds__(512) void k2_adj(
    const float* __restrict__ p1t,
    const float* __restrict__ p2b,
    const float* __restrict__ rel_w2,
    const float* __restrict__ rel_b2,
    float* __restrict__ araw,     // d_out A region (raw; normalized in k3)
    float* __restrict__ rdv)
{
    __shared__ float sp2[HH];
    __shared__ float sw2[HH];
    __shared__ float sred[8];
    const int t = threadIdx.x;    // j
    const int i = blockIdx.x;

    if (t < HH)          sp2[t] = p2b[(size_t)i * HH + t];
    else if (t < 2 * HH) sw2[t - HH] = rel_w2[t - HH];
    __syncthreads();

    float a = rel_b2[0];
    #pragma unroll
    for (int k = 0; k < HH; ++k) {
        float pv = p1t[(size_t)k * NN + t];    // 256B coalesced per wave
        a = fmaf(fmaxf(pv + sp2[k], 0.f), sw2[k], a);
    }
    a = 1.f / (1.f + expf(-a));
    if (t == i) a += 1.f;
    araw[(size_t)i * NN + t] = a;

    float rs = a;
    #pragma unroll
    for (int off = 32; off > 0; off >>= 1) rs += __shfl_down(rs, off, 64);
    const int wv = t >> 6, ln = t & 63;
    if (ln == 0) sred[wv] = rs;
    __syncthreads();
    if (t == 0) {
        float s = 0.f;
        #pragma unroll
        for (int w = 0; w < 8; ++w) s += sred[w];
        rdv[i] = 1.0f / sqrtf(s + 1.0f);
    }
}

// K3: block = row i (512 blocks x 512 thr). Normalize A row (LDS-cached),
// then x[i,o] = BN(relu?)… : o = t&31, 16 j-chunks of 32; LDS reduce.
__global__ __launch_bounds__(512) void k3_gcn(
    const float* __restrict__ xw,
    const float* __restrict__ rdv,
    const float* __restrict__ gcn_b,
    const float* __restrict__ bn_gamma,
    const float* __restrict__ bn_beta,
    float* __restrict__ outx,
    float* __restrict__ outA)
{
    __shared__ float sdv[NN];
    __shared__ float sA[NN];
    __shared__ float sred[16][33];
    const int t = threadIdx.x;    // j
    const int i = blockIdx.x;

    sdv[t] = rdv[t];
    __syncthreads();

    const float an = outA[(size_t)i * NN + t] * (sdv[i] * sdv[t]);
    outA[(size_t)i * NN + t] = an;
    sA[t] = an;
    __syncthreads();

    const int o  = t & 31;
    const int ch = t >> 5;        // 16 chunks of 32 j
    float acc = 0.f;
    #pragma unroll
    for (int jj = 0; jj < 32; ++jj) {
        int j = ch * 32 + jj;
        acc = fmaf(sA[j], xw[(size_t)j * OUTC + o], acc);  // 128B/group
    }
    sred[ch][o] = acc;
    __syncthreads();

    if (t < OUTC) {
        float v = gcn_b[t];
        #pragma unroll
        for (int c = 0; c < 16; ++c) v += sred[c][t];
        const float invs = 1.0f / sqrtf(1.0f + 1e-5f);
        v = bn_gamma[t] * v * invs + bn_beta[t];
        outx[(size_t)i * OUTC + t] = fmaxf(v, 0.f);
    }
}

extern "C" void kernel_launch(void* const* d_in, const int* in_sizes, int n_in,
                              void* d_out, int out_size, void* d_ws, size_t ws_size,
                              hipStream_t stream) {
    const float* features = (const float*)d_in[0];
    const float* rel_w1   = (const float*)d_in[1];
    const float* rel_b1   = (const float*)d_in[2];
    const float* rel_w2   = (const float*)d_in[3];
    const float* rel_b2   = (const float*)d_in[4];
    const float* gcn_w    = (const float*)d_in[5];
    const float* gcn_b    = (const float*)d_in[6];
    const float* bn_gamma = (const float*)d_in[7];
    const float* bn_beta  = (const float*)d_in[8];

    float* out  = (float*)d_out;
    float* outx = out;                 // (512, 32)
    float* outA = out + NN * OUTC;     // (512, 512)

    float* ws  = (float*)d_ws;
    float* p1t = ws;                   // [64][512] col-major
    float* p2b = ws + 32768;           // [512][64]
    float* xw  = ws + 65536;           // [512][32] row-major
    float* rdv = ws + 81920;           // [512]

    hipLaunchKernelGGL(k1_gemm, dim3(5, 512), dim3(256), 0, stream,
                       features, rel_w1, rel_b1, gcn_w, p1t, p2b, xw);
    hipLaunchKernelGGL(k2_adj, dim3(512), dim3(512), 0, stream,
                       p1t, p2b, rel_w2, rel_b2, outA, rdv);
    hipLaunchKernelGGL(k3_gcn, dim3(512), dim3(512), 0, stream,
                       xw, rdv, gcn_b, bn_gamma, bn_beta, outx, outA);
}

// Round 9
// 25.704 us; speedup vs baseline: 7.1668x; 1.1176x over previous
//
#include <hip/hip_runtime.h>
#include <math.h>

#define NN 512
#define DD 512
#define HH 64
#define OUTC 32

// ws layout (floats):
//   P1T  [H][N]   @ 0      (32768)   col-major: P1T[h][j] (k2 reads coalesced)
//   P2B  [N][H]   @ 32768  (32768)   row-major
//   XW   [N][OUT] @ 65536  (16384)   row-major: XW[j][o] (k3 reads coalesced)
//   RDV  [N]      @ 81920  (512)

// K1: C[512][160] = F @ [W1a | W1b | gcn_w], split-K 32, 4 cols x 4 ROWS per
// thread. Each W float4 feeds 16 FMAs (4 rows), cutting W L2 traffic 4x
// (169 -> 42 MB). grid (cg=0..4, it=0..127) x 256 thr.
// thread: tq = t&7 (col quad), kc = t>>3 (16 k-terms).
template<int STRIDE>
__device__ __forceinline__ void dotrows(const float* __restrict__ fp,   // rows i0..i0+3
                                        const float* __restrict__ wp,
                                        float4 acc[4])
{
    float4 fr[4][4];
    #pragma unroll
    for (int r = 0; r < 4; ++r)
        #pragma unroll
        for (int q = 0; q < 4; ++q)
            fr[r][q] = *(const float4*)(fp + (size_t)r * DD + 4 * q);

    #pragma unroll
    for (int q = 0; q < 16; ++q) {
        float4 w = *(const float4*)(wp + (size_t)q * STRIDE);
        #pragma unroll
        for (int r = 0; r < 4; ++r) {
            float f = (q < 4 ? (q == 0 ? fr[r][0].x : q == 1 ? fr[r][0].y : q == 2 ? fr[r][0].z : fr[r][0].w)
                     : q < 8 ? (q == 4 ? fr[r][1].x : q == 5 ? fr[r][1].y : q == 6 ? fr[r][1].z : fr[r][1].w)
                     : q < 12 ? (q == 8 ? fr[r][2].x : q == 9 ? fr[r][2].y : q == 10 ? fr[r][2].z : fr[r][2].w)
                     : (q == 12 ? fr[r][3].x : q == 13 ? fr[r][3].y : q == 14 ? fr[r][3].z : fr[r][3].w));
            acc[r].x = fmaf(f, w.x, acc[r].x);
            acc[r].y = fmaf(f, w.y, acc[r].y);
            acc[r].z = fmaf(f, w.z, acc[r].z);
            acc[r].w = fmaf(f, w.w, acc[r].w);
        }
    }
}

__global__ __launch_bounds__(256) void k1_gemm(
    const float* __restrict__ features,
    const float* __restrict__ rel_w1,
    const float* __restrict__ rel_b1,
    const float* __restrict__ gcn_w,
    float* __restrict__ p1t,
    float* __restrict__ p2b,
    float* __restrict__ xw)
{
    __shared__ float sred[4][32][33];    // [row][kc][col], padded
    const int t  = threadIdx.x;
    const int tq = t & 7;
    const int kc = t >> 3;
    const int cg = blockIdx.x;           // 0..4
    const int i0 = blockIdx.y * 4;       // 4 rows per block

    const float* fp = features + (size_t)i0 * DD + kc * 16;

    float4 acc[4];
    #pragma unroll
    for (int r = 0; r < 4; ++r) acc[r] = make_float4(0.f, 0.f, 0.f, 0.f);

    if (cg < 2)
        dotrows<HH>(fp, rel_w1 + cg * 32 + tq * 4 + (size_t)kc * 16 * HH, acc);
    else if (cg < 4)
        dotrows<HH>(fp, rel_w1 + (size_t)DD * HH + (cg - 2) * 32 + tq * 4
                        + (size_t)kc * 16 * HH, acc);
    else
        dotrows<OUTC>(fp, gcn_w + tq * 4 + (size_t)kc * 16 * OUTC, acc);

    #pragma unroll
    for (int r = 0; r < 4; ++r) {
        sred[r][kc][tq * 4 + 0] = acc[r].x;
        sred[r][kc][tq * 4 + 1] = acc[r].y;
        sred[r][kc][tq * 4 + 2] = acc[r].z;
        sred[r][kc][tq * 4 + 3] = acc[r].w;
    }
    __syncthreads();

    if (t < 128) {
        const int r = t >> 5, c = t & 31;
        const int i = i0 + r;
        float s = 0.f;
        #pragma unroll
        for (int k = 0; k < 32; ++k) s += sred[r][k][c];
        if (cg < 2) {
            p1t[(size_t)(cg * 32 + c) * NN + i] = s;       // col-major
        } else if (cg < 4) {
            int h = (cg - 2) * 32 + c;
            p2b[(size_t)i * HH + h] = s + rel_b1[h];
        } else {
            xw[(size_t)i * OUTC + c] = s;                  // row-major
        }
    }
}

// K2: 2 rows per block (256 blocks x 512 thr), thread = col j; every p1t
// load feeds both rows. araw[i][j] = sigmoid(relu(P1[j]+P2b[i]).w2+b2)+(i==j).
__global__ __launch_bounds__(512) void k2_adj(
    const float* __restrict__ p1t,
    const float* __restrict__ p2b,
    const float* __restrict__ rel_w2,
    const float* __restrict__ rel_b2,
    float* __restrict__ araw,     // d_out A region (raw; normalized in k3)
    float* __restrict__ rdv)
{
    __shared__ float sp2[2][HH];
    __shared__ float sw2[HH];
    __shared__ float sred[2][8];
    const int t  = threadIdx.x;   // j
    const int i0 = blockIdx.x * 2;

    if (t < HH)            sp2[0][t] = p2b[(size_t)i0 * HH + t];
    else if (t < 2 * HH)   sp2[1][t - HH] = p2b[(size_t)(i0 + 1) * HH + (t - HH)];
    else if (t < 3 * HH)   sw2[t - 2 * HH] = rel_w2[t - 2 * HH];
    __syncthreads();

    float a0 = rel_b2[0], a1 = a0;
    #pragma unroll
    for (int k = 0; k < HH; ++k) {
        float pv = p1t[(size_t)k * NN + t];    // 256B coalesced per wave
        float w  = sw2[k];
        a0 = fmaf(fmaxf(pv + sp2[0][k], 0.f), w, a0);
        a1 = fmaf(fmaxf(pv + sp2[1][k], 0.f), w, a1);
    }
    a0 = 1.f / (1.f + expf(-a0));
    a1 = 1.f / (1.f + expf(-a1));
    if (t == i0)     a0 += 1.f;
    if (t == i0 + 1) a1 += 1.f;
    araw[(size_t)i0 * NN + t]       = a0;
    araw[(size_t)(i0 + 1) * NN + t] = a1;

    float rs0 = a0, rs1 = a1;
    #pragma unroll
    for (int off = 32; off > 0; off >>= 1) {
        rs0 += __shfl_down(rs0, off, 64);
        rs1 += __shfl_down(rs1, off, 64);
    }
    const int wv = t >> 6, ln = t & 63;
    if (ln == 0) { sred[0][wv] = rs0; sred[1][wv] = rs1; }
    __syncthreads();
    if (t < 2) {
        float s = 0.f;
        #pragma unroll
        for (int w = 0; w < 8; ++w) s += sred[t][w];
        rdv[i0 + t] = 1.0f / sqrtf(s + 1.0f);
    }
}

// K3: block = row i (512 blocks x 512 thr). Normalize A row (LDS-cached),
// then x[i,o]: o = t&31, 16 j-chunks of 32; LDS reduce; BN+ReLU.
__global__ __launch_bounds__(512) void k3_gcn(
    const float* __restrict__ xw,
    const float* __restrict__ rdv,
    const float* __restrict__ gcn_b,
    const float* __restrict__ bn_gamma,
    const float* __restrict__ bn_beta,
    float* __restrict__ outx,
    float* __restrict__ outA)
{
    __shared__ float sdv[NN];
    __shared__ float sA[NN];
    __shared__ float sred[16][33];
    const int t = threadIdx.x;    // j
    const int i = blockIdx.x;

    sdv[t] = rdv[t];
    __syncthreads();

    const float an = outA[(size_t)i * NN + t] * (sdv[i] * sdv[t]);
    outA[(size_t)i * NN + t] = an;
    sA[t] = an;
    __syncthreads();

    const int o  = t & 31;
    const int ch = t >> 5;        // 16 chunks of 32 j
    float acc = 0.f;
    #pragma unroll
    for (int jj = 0; jj < 32; ++jj) {
        int j = ch * 32 + jj;
        acc = fmaf(sA[j], xw[(size_t)j * OUTC + o], acc);  // 128B/group
    }
    sred[ch][o] = acc;
    __syncthreads();

    if (t < OUTC) {
        float v = gcn_b[t];
        #pragma unroll
        for (int c = 0; c < 16; ++c) v += sred[c][t];
        const float invs = 1.0f / sqrtf(1.0f + 1e-5f);
        v = bn_gamma[t] * v * invs + bn_beta[t];
        outx[(size_t)i * OUTC + t] = fmaxf(v, 0.f);
    }
}

extern "C" void kernel_launch(void* const* d_in, const int* in_sizes, int n_in,
                              void* d_out, int out_size, void* d_ws, size_t ws_size,
                              hipStream_t stream) {
    const float* features = (const float*)d_in[0];
    const float* rel_w1   = (const float*)d_in[1];
    const float* rel_b1   = (const float*)d_in[2];
    const float* rel_w2   = (const float*)d_in[3];
    const float* rel_b2   = (const float*)d_in[4];
    const float* gcn_w    = (const float*)d_in[5];
    const float* gcn_b    = (const float*)d_in[6];
    const float* bn_gamma = (const float*)d_in[7];
    const float* bn_beta  = (const float*)d_in[8];

    float* out  = (float*)d_out;
    float* outx = out;                 // (512, 32)
    float* outA = out + NN * OUTC;     // (512, 512)

    float* ws  = (float*)d_ws;
    float* p1t = ws;                   // [64][512] col-major
    float* p2b = ws + 32768;           // [512][64]
    float* xw  = ws + 65536;           // [512][32] row-major
    float* rdv = ws + 81920;           // [512]

    hipLaunchKernelGGL(k1_gemm, dim3(5, 128), dim3(256), 0, stream,
                       features, rel_w1, rel_b1, gcn_w, p1t, p2b, xw);
    hipLaunchKernelGGL(k2_adj, dim3(256), dim3(512), 0, stream,
                       p1t, p2b, rel_w2, rel_b2, outA, rdv);
    hipLaunchKernelGGL(k3_gcn, dim3(512), dim3(512), 0, stream,
                       xw, rdv, gcn_b, bn_gamma, bn_beta, outx, outA);
}